// Round 12
// baseline (263.562 us; speedup 1.0000x reference)
//
#include <hip/hip_runtime.h>

#define NUM_P 16320
#define NUM_C 21
#define THETA 0.01f
#define NTILE 16          // 15 sub-tiles of 1024 anchors + 1 of 960

// One block per batch row. Streams conf through LDS, CE in registers,
// in-block 2-level radix top-k, device-atomic finalize.
__global__ __launch_bounds__(1024) void fused_kernel(
    const float* __restrict__ loc, const float* __restrict__ conf,
    const float* __restrict__ arm, const float* __restrict__ loct,
    const int* __restrict__ conft,
    float* __restrict__ acc,      // [0]=L [1]=C ; int view: [2]=N [3]=ctr
    float* __restrict__ out)
{
    __shared__ float tile[1024 * NUM_C];     // 86016 B
    __shared__ int hist1[256];
    __shared__ int hist2[2048];
    __shared__ float wred[16], sll[16], scc[16];
    __shared__ int sni[16];
    __shared__ int s_b1, s_kk1, s_t19, s_kk2;

    const int b = blockIdx.x;
    const int tid = threadIdx.x;
    const int lane = tid & 63, w = tid >> 6;
    const size_t rowbase = (size_t)b * NUM_P;

    unsigned cebits[NTILE];      // statically indexed (full unroll below)
    float ll = 0.f, cep = 0.f;
    int cnt = 0;

    // ---------------- phase 1: stream row, compute CE into registers --------
    float4 rr[6];
    int tc = 0; float2 av = make_float2(0.f, 0.f);
    {
        const float4* conf4 = (const float4*)(conf + rowbase * NUM_C);
        #pragma unroll
        for (int k = 0; k < 6; ++k) {
            const int i = tid + k * 1024;
            if (i < 5376) rr[k] = conf4[i];          // 1024*21/4
        }
        tc = conft[rowbase + tid];
        av = ((const float2*)arm)[rowbase + tid];
    }

    #pragma unroll
    for (int it = 0; it < NTILE; ++it) {
        const int tsize = (it < NTILE - 1) ? 1024 : 960;
        const int nfl4  = tsize * NUM_C / 4;         // 5376 or 5040
        {
            float4* tile4 = (float4*)tile;
            #pragma unroll
            for (int k = 0; k < 6; ++k) {
                const int i = tid + k * 1024;
                if (i < nfl4) tile4[i] = rr[k];
            }
        }
        const int tcl = tc; const float2 avl = av;   // save before refill
        __syncthreads();                             // tile visible

        // prefetch next sub-tile (overlaps compute)
        if (it + 1 < NTILE) {
            const int nsize = (it + 1 < NTILE - 1) ? 1024 : 960;
            const int nn4 = nsize * NUM_C / 4;
            const size_t nb = rowbase + (size_t)(it + 1) * 1024;
            const float4* conf4 = (const float4*)(conf + nb * NUM_C);
            #pragma unroll
            for (int k = 0; k < 6; ++k) {
                const int i = tid + k * 1024;
                if (i < nn4) rr[k] = conf4[i];
            }
            if (tid < nsize) {
                tc = conft[nb + tid];
                av = ((const float2*)arm)[nb + tid];
            }
        }

        unsigned rb = 0u;
        if (tid < tsize) {
            const float* cf = &tile[tid * NUM_C];    // stride 21: conflict-free
            float mx = cf[0];
            #pragma unroll
            for (int j = 1; j < NUM_C; ++j) mx = fmaxf(mx, cf[j]);
            float s = 0.f;
            #pragma unroll
            for (int j = 0; j < NUM_C; ++j) s += __expf(cf[j] - mx);
            const float ce = mx + __logf(s) - cf[tcl];

            const float am = fmaxf(avl.x, avl.y);
            const float e0 = __expf(avl.x - am), e1 = __expf(avl.y - am);
            const bool pos = (tcl > 0) && (e1 / (e0 + e1) > THETA);

            if (pos) {
                ++cnt; cep += ce;
                const size_t a = rowbase + (size_t)it * 1024 + tid;
                const float4 lv = ((const float4*)loc)[a];
                const float4 tv = ((const float4*)loct)[a];
                const float dx[4] = { lv.x-tv.x, lv.y-tv.y, lv.z-tv.z, lv.w-tv.w };
                #pragma unroll
                for (int j = 0; j < 4; ++j) {
                    const float ad = fabsf(dx[j]);
                    ll += (ad < 1.f) ? 0.5f * ad * ad : ad - 0.5f;
                }
            } else {
                rb = __float_as_uint(ce);            // loss_for_rank bits (>=0)
            }
        }
        cebits[it] = rb;
        __syncthreads();                             // reads done before overwrite
    }

    // ---------------- phase 2: block reductions ----------------
    #pragma unroll
    for (int off = 32; off > 0; off >>= 1) {
        cnt += __shfl_down(cnt, off, 64);
        ll  += __shfl_down(ll, off, 64);
        cep += __shfl_down(cep, off, 64);
    }
    if (lane == 0) { sni[w] = cnt; sll[w] = ll; scc[w] = cep; }
    if (tid < 256) hist1[tid] = 0;
    hist2[tid] = 0; hist2[tid + 1024] = 0;
    __syncthreads();

    int np = 0;
    #pragma unroll
    for (int i = 0; i < 16; ++i) np += sni[i];       // broadcast reads, uniform
    const int k = min(3 * np, NUM_P - 1);
    float tot = 0.f;

    if (k > 0) {        // block-uniform
        // ---- level 1: top-byte histogram, ballot-aggregated (few bins) ----
        #pragma unroll
        for (int it = 0; it < NTILE; ++it) {
            const unsigned bin = cebits[it] >> 24;
            unsigned long long alive = ~0ULL;
            while (alive) {
                const int leader = __ffsll(alive) - 1;
                const unsigned lb = __shfl(bin, leader, 64);
                const unsigned long long mm = __ballot(bin == lb);
                if (lane == leader) atomicAdd(&hist1[lb], (int)__popcll(mm));
                alive &= ~mm;
            }
        }
        __syncthreads();
        if (tid < 64) {          // suffix scan + unique selection (wave 0)
            const int j0 = tid * 4;
            const int h0 = hist1[j0], h1 = hist1[j0+1], h2 = hist1[j0+2], h3 = hist1[j0+3];
            int ssum = h0 + h1 + h2 + h3;
            #pragma unroll
            for (int d = 1; d < 64; d <<= 1) {
                const int tmp = __shfl_down(ssum, d, 64);
                if (lane + d < 64) ssum += tmp;
            }
            const int bse = ssum - (h0 + h1 + h2 + h3);
            int S[5];
            S[0] = ssum; S[4] = bse;
            S[3] = bse + h3; S[2] = S[3] + h2; S[1] = S[2] + h1;
            #pragma unroll
            for (int jj = 0; jj < 4; ++jj)
                if (S[jj] >= k && S[jj + 1] < k) { s_b1 = j0 + jj; s_kk1 = k - S[jj + 1]; }
        }
        __syncthreads();
        const unsigned B1 = (unsigned)s_b1;
        const int kk1 = s_kk1;

        // ---- level 2: 2048-bin hist of bits 23..13 among B1 elements ----
        #pragma unroll
        for (int it = 0; it < NTILE; ++it) {
            const unsigned u = cebits[it];
            if ((u >> 24) == B1) atomicAdd(&hist2[(u >> 13) & 0x7FFu], 1);
        }
        __syncthreads();
        const int h0 = hist2[2 * tid], h1 = hist2[2 * tid + 1];
        int suf = h0 + h1;
        #pragma unroll
        for (int d = 1; d < 64; d <<= 1) {
            const int tmp = __shfl_down(suf, d, 64);
            if (lane + d < 64) suf += tmp;
        }
        if (lane == 0) hist1[w] = suf;               // reuse as wave totals
        __syncthreads();
        int woff = 0;
        for (int ww = w + 1; ww < 16; ++ww) woff += hist1[ww];
        const int S0 = suf + woff, S1 = S0 - h0, S2 = S1 - h1;
        if (S0 >= kk1 && S1 < kk1) { s_t19 = ((int)B1 << 11) | (2 * tid);     s_kk2 = kk1 - S1; }
        if (S1 >= kk1 && S2 < kk1) { s_t19 = ((int)B1 << 11) | (2 * tid + 1); s_kk2 = kk1 - S2; }
        __syncthreads();
        const unsigned t19 = (unsigned)s_t19;
        const float vth = __uint_as_float(t19 << 13);   // bin lower edge

        float partial = 0.f;
        #pragma unroll
        for (int it = 0; it < NTILE; ++it)
            if ((cebits[it] >> 13) > t19) partial += __uint_as_float(cebits[it]);
        #pragma unroll
        for (int off = 32; off > 0; off >>= 1)
            partial += __shfl_down(partial, off, 64);
        if (lane == 0) wred[w] = partial;
        __syncthreads();
        if (tid == 0) {
            #pragma unroll
            for (int i = 0; i < 16; ++i) tot += wred[i];
            tot += (float)s_kk2 * vth;               // ties at threshold (bin-edge)
        }
    }

    // ---------------- phase 3: device-atomic contribution + finalize --------
    if (tid == 0) {
        float SL = 0.f, SC = 0.f;
        #pragma unroll
        for (int i = 0; i < 16; ++i) { SL += sll[i]; SC += scc[i]; }
        int* acc_i = (int*)acc;
        atomicAdd(&acc[0], SL);
        atomicAdd(&acc[1], SC + tot);
        atomicAdd(&acc_i[2], np);
        __threadfence();
        const int prev = atomicAdd(&acc_i[3], 1);
        if (prev == (int)gridDim.x - 1) {            // last block finalizes
            __threadfence();
            const float L = atomicAdd(&acc[0], 0.f);
            const float C = atomicAdd(&acc[1], 0.f);
            const int   N = atomicAdd(&acc_i[2], 0);
            out[0] = L / (float)N;
            out[1] = C / (float)N;
        }
    }
}

extern "C" void kernel_launch(void* const* d_in, const int* in_sizes, int n_in,
                              void* d_out, int out_size, void* d_ws, size_t ws_size,
                              hipStream_t stream) {
    const float* loc  = (const float*)d_in[0];
    const float* conf = (const float*)d_in[1];
    const float* arm  = (const float*)d_in[2];
    const float* loct = (const float*)d_in[3];
    const int*  conft = (const int*)d_in[4];
    float* out = (float*)d_out;

    const int total = in_sizes[4];     // B * P
    const int Bn = total / NUM_P;      // 64 rows

    float* acc = (float*)d_ws;         // [0]=L [1]=C [2]=N(int) [3]=ctr(int)
    hipMemsetAsync(d_ws, 0, 64, stream);

    hipLaunchKernelGGL(fused_kernel, dim3(Bn), dim3(1024), 0, stream,
                       loc, conf, arm, loct, conft, acc, out);
}